// Round 16
// baseline (215.064 us; speedup 1.0000x reference)
//
#include <hip/hip_runtime.h>
#include <hip/hip_bf16.h>

#define S1 2048
#define S2 2048
#define FEAT 768
#define NB 8
#define BK 32
#define NKT (FEAT / BK)          // 24 K-steps

typedef __attribute__((ext_vector_type(8))) short bf16x8;
typedef __attribute__((ext_vector_type(4))) float f32x4;
typedef __attribute__((ext_vector_type(4))) unsigned short us4;

static __device__ __forceinline__ unsigned short f2bf(float x) {
    unsigned u = __builtin_bit_cast(unsigned, x);
    unsigned r = u + 0x7FFFu + ((u >> 16) & 1u);   // RNE
    return (unsigned short)(r >> 16);
}

// ---------------- prepass: A=bf16(m1*wc), B=bf16(m2), Q=m1@wq, D=m2@wd ----------------
__global__ __launch_bounds__(256) void conv_kernel(
    const float* __restrict__ m1, const float* __restrict__ m2,
    const float* __restrict__ wq, const float* __restrict__ wd,
    const float* __restrict__ wc,
    unsigned short* __restrict__ A, unsigned short* __restrict__ Bm,
    float* __restrict__ Q, float* __restrict__ D) {
    int wave = threadIdx.x >> 6;
    int lane = threadIdx.x & 63;
    int g = blockIdx.x * 4 + wave;               // 0 .. 2*NB*S1-1
    bool isA = (g < NB * S1);
    int row = isA ? g : g - NB * S1;
    const float* src = isA ? m1 : m2;
    const float* w   = isA ? wq : wd;
    unsigned short* dst = (isA ? A : Bm) + (size_t)row * FEAT;
    const float4* rp = (const float4*)(src + (size_t)row * FEAT);
    const float4* wp = (const float4*)w;
    const float4* cp = (const float4*)wc;
    float acc = 0.f;
#pragma unroll
    for (int i = 0; i < 3; ++i) {
        int idx = lane + 64 * i;
        float4 a = rp[idx];
        float4 b = wp[idx];
        acc += a.x * b.x + a.y * b.y + a.z * b.z + a.w * b.w;
        float4 c;
        if (isA) c = cp[idx]; else c = float4{1.f, 1.f, 1.f, 1.f};
        us4 v = { f2bf(a.x * c.x), f2bf(a.y * c.y),
                  f2bf(a.z * c.z), f2bf(a.w * c.w) };
        *(us4*)(dst + idx * 4) = v;
    }
#pragma unroll
    for (int s = 32; s; s >>= 1) acc += __shfl_xor(acc, s, 64);
    if (lane == 0) (isA ? Q : D)[row] = acc;
}

// ---------------- 128x128 tile, ZERO-LDS direct-from-global GEMM ----------------
// R16: remove the staging apparatus entirely (guide Common-mistake #7:
// "LDS-staging data that L2-fits is pure overhead" -- FETCH pinned at the
// 43 MB operand minimum since R2 proves panels are cache-resident; quadrant
// walk keeps the per-XCD window ~3 MB < 4 MB L2).
// NT GEMM with K-major operands means the MFMA fragment (16 rows x 16
// contiguous K-bytes per lane) IS the global layout: af[m]/bf[n] are plain
// global_load_dwordx4 (16 x 64 B segments each, same txn count as staged).
// => no global_load_lds, no ds_read, no barrier, no waitcnt discipline.
// Compiler software-pipelines the fully-unrolled K-loop with its own
// counted vmcnt. Occupancy: LDS=0, VGPR-bound only (4 blocks/CU).
__global__ __launch_bounds__(256, 4) void gemm128g_kernel(
    const unsigned short* __restrict__ A, const unsigned short* __restrict__ Bm,
    const float* __restrict__ Q, const float* __restrict__ D,
    float* __restrict__ out) {

    // XCD owns batch (bid&7); within XCD walk 8x8 quadrants (R7/R8-proven).
    const int bid = blockIdx.x;                    // 0..2047
    const int b   = bid & 7;                       // batch == XCD
    const int idx = bid >> 3;                      // 0..255
    const int qd  = idx >> 6;                      // quadrant 0..3
    const int w64 = idx & 63;
    const int tm  = ((qd >> 1) << 3) | (w64 >> 3);
    const int tn  = ((qd & 1) << 3) | (w64 & 7);

    const int tid  = threadIdx.x;
    const int lane = tid & 63;
    const int wave = tid >> 6;
    const int wm = wave >> 1, wn = wave & 1;       // 2x2 waves, 64x64 out each

    const int fr = lane & 15;                      // fragment row
    const int kg = lane >> 4;                      // K-group 0..3 (8 bf16 each)

    // per-lane fragment base pointers: row-major [row][K], 1536 B rows
    const char* Arow = (const char*)(A + ((size_t)b * S1 + (size_t)tm * 128
                                          + wm * 64 + fr) * FEAT) + kg * 16;
    const char* Brow = (const char*)(Bm + ((size_t)b * S2 + (size_t)tn * 128
                                          + wn * 64 + fr) * FEAT) + kg * 16;

    f32x4 acc[4][4];
#pragma unroll
    for (int m = 0; m < 4; ++m)
#pragma unroll
        for (int n = 0; n < 4; ++n) acc[m][n] = (f32x4)0.f;

#pragma unroll
    for (int kt = 0; kt < NKT; ++kt) {             // K-step = 32 (64 B per row)
        bf16x8 af[4], bf[4];
#pragma unroll
        for (int m = 0; m < 4; ++m)
            af[m] = *(const bf16x8*)(Arow + (size_t)m * (16 * FEAT * 2) + kt * 64);
#pragma unroll
        for (int n = 0; n < 4; ++n)
            bf[n] = *(const bf16x8*)(Brow + (size_t)n * (16 * FEAT * 2) + kt * 64);
#pragma unroll
        for (int m = 0; m < 4; ++m)
#pragma unroll
            for (int n = 0; n < 4; ++n)
                acc[m][n] = __builtin_amdgcn_mfma_f32_16x16x32_bf16(
                    af[m], bf[n], acc[m][n], 0, 0, 0);
    }

    // ---------------- epilogue: + Q[j] + D[k], store fp32 ----------------
    const float* Qb = Q + b * S1 + tm * 128;
    const float* Db = D + b * S2 + tn * 128;
    float dv[4];
#pragma unroll
    for (int n = 0; n < 4; ++n) dv[n] = Db[wn * 64 + n * 16 + fr];

    const size_t outbase = ((size_t)b * S1 + (size_t)tm * 128) * S2 + (size_t)tn * 128;
#pragma unroll
    for (int m = 0; m < 4; ++m) {
#pragma unroll
        for (int i = 0; i < 4; ++i) {
            int rl = wm * 64 + m * 16 + kg * 4 + i;
            float qv = Qb[rl];
            float* orow = out + outbase + (size_t)rl * S2 + wn * 64;
#pragma unroll
            for (int n = 0; n < 4; ++n)
                orow[n * 16 + fr] = acc[m][n][i] + qv + dv[n];
        }
    }
}

// ================= fallback path (round-1, fp32 inputs) =================
__global__ __launch_bounds__(256) void qd_kernel(
    const float* __restrict__ m1, const float* __restrict__ m2,
    const float* __restrict__ wq, const float* __restrict__ wd,
    float* __restrict__ Q, float* __restrict__ D) {
    int wave = threadIdx.x >> 6;
    int lane = threadIdx.x & 63;
    int g = blockIdx.x * 4 + wave;
    const float* src; const float* w; float* dst; int row;
    if (g < NB * S1) { src = m1; w = wq; dst = Q; row = g; }
    else             { src = m2; w = wd; dst = D; row = g - NB * S1; }
    const float4* rp = (const float4*)(src + (size_t)row * FEAT);
    const float4* wp = (const float4*)w;
    float acc = 0.f;
#pragma unroll
    for (int i = 0; i < 3; ++i) {
        float4 a = rp[lane + 64 * i];
        float4 b = wp[lane + 64 * i];
        acc += a.x * b.x + a.y * b.y + a.z * b.z + a.w * b.w;
    }
#pragma unroll
    for (int s = 32; s; s >>= 1) acc += __shfl_xor(acc, s, 64);
    if (lane == 0) dst[row] = acc;
}

__global__ __launch_bounds__(256) void gemm_kernel(
    const float* __restrict__ m1, const float* __restrict__ m2,
    const float* __restrict__ wc,
    const float* __restrict__ Q, const float* __restrict__ D,
    float* __restrict__ out) {

    __shared__ __align__(16) char sA[128 * 64 * 2];
    __shared__ __align__(16) char sB[128 * 64 * 2];
    __shared__ float wcs[FEAT];

    const int tid = threadIdx.x;
    const int blk = blockIdx.x;
    const int b  = blk >> 8;
    const int t  = blk & 255;
    const int tm = t >> 4, tn = t & 15;

    for (int i = tid; i < FEAT; i += 256) wcs[i] = wc[i];

    const float* Abase = m1 + ((size_t)b * S1 + (size_t)tm * 128) * FEAT;
    const float* Bbase = m2 + ((size_t)b * S2 + (size_t)tn * 128) * FEAT;

    const int lane = tid & 63;
    const int wave = tid >> 6;
    const int wm = wave >> 1, wn = wave & 1;

    f32x4 acc[4][4];
#pragma unroll
    for (int m = 0; m < 4; ++m)
#pragma unroll
        for (int n = 0; n < 4; ++n) acc[m][n] = (f32x4)0.f;

    const int col4 = tid & 15;
    const int row0 = tid >> 4;

    __syncthreads();

    for (int ks = 0; ks < FEAT / 64; ++ks) {
        float4 wc4 = *(const float4*)&wcs[ks * 64 + col4 * 4];
        const float4* Ak = (const float4*)(Abase + ks * 64);
        const float4* Bk = (const float4*)(Bbase + ks * 64);

        __syncthreads();
#pragma unroll
        for (int i = 0; i < 8; ++i) {
            int r = row0 + 16 * i;
            float4 a = Ak[(size_t)r * (FEAT / 4) + col4];
            us4 av = { f2bf(a.x * wc4.x), f2bf(a.y * wc4.y),
                       f2bf(a.z * wc4.z), f2bf(a.w * wc4.w) };
            int off = r * 128 + ((col4 * 8) ^ ((r & 7) << 4));
            *(us4*)(sA + off) = av;
        }
#pragma unroll
        for (int i = 0; i < 8; ++i) {
            int r = row0 + 16 * i;
            float4 v = Bk[(size_t)r * (FEAT / 4) + col4];
            us4 bv = { f2bf(v.x), f2bf(v.y), f2bf(v.z), f2bf(v.w) };
            int off = r * 128 + ((col4 * 8) ^ ((r & 7) << 4));
            *(us4*)(sB + off) = bv;
        }
        __syncthreads();

#pragma unroll
        for (int s = 0; s < 2; ++s) {
            bf16x8 af[4], bfr[4];
#pragma unroll
            for (int m = 0; m < 4; ++m) {
                int r = wm * 64 + m * 16 + (lane & 15);
                int coff = (s * 64 + (lane >> 4) * 16) ^ ((r & 7) << 4);
                af[m] = *(const bf16x8*)(sA + r * 128 + coff);
            }
#pragma unroll
            for (int n = 0; n < 4; ++n) {
                int r = wn * 64 + n * 16 + (lane & 15);
                int coff = (s * 64 + (lane >> 4) * 16) ^ ((r & 7) << 4);
                bfr[n] = *(const bf16x8*)(sB + r * 128 + coff);
            }
#pragma unroll
            for (int m = 0; m < 4; ++m)
#pragma unroll
                for (int n = 0; n < 4; ++n)
                    acc[m][n] = __builtin_amdgcn_mfma_f32_16x16x32_bf16(
                        af[m], bfr[n], acc[m][n], 0, 0, 0);
        }
    }

    const float* Qb = Q + b * S1 + tm * 128;
    const float* Db = D + b * S2 + tn * 128;
    float dv[4];
#pragma unroll
    for (int n = 0; n < 4; ++n) dv[n] = Db[wn * 64 + n * 16 + (lane & 15)];

    const size_t outbase = ((size_t)b * S1 + (size_t)tm * 128) * S2 + (size_t)tn * 128;
#pragma unroll
    for (int m = 0; m < 4; ++m) {
#pragma unroll
        for (int i = 0; i < 4; ++i) {
            int rl = wm * 64 + m * 16 + (lane >> 4) * 4 + i;
            float qv = Qb[rl];
            float* orow = out + outbase + (size_t)rl * S2 + wn * 64;
#pragma unroll
            for (int n = 0; n < 4; ++n) {
                int cl = n * 16 + (lane & 15);
                orow[cl] = acc[m][n][i] + qv + dv[n];
            }
        }
    }
}

extern "C" void kernel_launch(void* const* d_in, const int* in_sizes, int n_in,
                              void* d_out, int out_size, void* d_ws, size_t ws_size,
                              hipStream_t stream) {
    const float* m1 = (const float*)d_in[0];
    const float* m2 = (const float*)d_in[1];
    const float* wq = (const float*)d_in[2];
    const float* wd = (const float*)d_in[3];
    const float* wc = (const float*)d_in[4];
    float* out = (float*)d_out;

    const size_t elems = (size_t)NB * S1 * FEAT;
    const size_t need = 2 * elems * sizeof(unsigned short)
                      + (size_t)(NB * S1 + NB * S2) * sizeof(float);

    if (ws_size >= need) {
        unsigned short* Abuf = (unsigned short*)d_ws;
        unsigned short* Bbuf = Abuf + elems;
        float* Q  = (float*)(Bbuf + elems);
        float* Dv = Q + NB * S1;
        conv_kernel<<<(NB * S1 + NB * S2) / 4, 256, 0, stream>>>(
            m1, m2, wq, wd, wc, Abuf, Bbuf, Q, Dv);
        gemm128g_kernel<<<NB * 16 * 16, 256, 0, stream>>>(Abuf, Bbuf, Q, Dv, out);
    } else {
        float* Q  = (float*)d_ws;
        float* Dv = Q + NB * S1;
        qd_kernel<<<(2 * NB * S1) / 4, 256, 0, stream>>>(m1, m2, wq, wd, Q, Dv);
        gemm_kernel<<<NB * 256, 256, 0, stream>>>(m1, m2, wc, Q, Dv, out);
    }
}